// Round 9
// baseline (4106.590 us; speedup 1.0000x reference)
//
#include <hip/hip_runtime.h>

// EdgeNetwork fused MLP on MI355X — register-chained swapped-operand MFMA (bf16 hi/lo split).
// B=8, N=50000, E=200000, D=16, H=128.
// D = W(A-role) x X(B-role) per layer with mfma_f32_16x16x32_bf16: the C/D layout
// (col=lane&15=edge, row=4*(lane>>4)+reg=feature) IS the next layer's B-fragment layout,
// so activations chain in registers. fp32 = bf16_hi+lo, 3 MFMAs/product.
// Weights staged once per persistent block into 149KB dynamic LDS (XOR-swizzled).
//
// HISTORY R5-R8: 7GB FETCH + 1.5GB WRITE scratch traffic, dur==hbm_bytes/BW, VGPR pinned
// at 128 across launch_bounds variants, amdgpu_waves_per_eu(2,2), and a full no-arrays
// named-variable rewrite (R8). Scratch re-read arithmetic (2.1KB/lane/tile = 2 layers x
// 4 chunks x 256B state) says the allocator keeps MFMA state in scratch within a 128-reg
// ceiling no knob lifts.
// R9 FIX: shrink demand below the ceiling instead of fighting it. 16 edges/wave (one
// 16-col MFMA block): acc 32 + frags 32 + gather 8 + temps ~30 = ~100 VGPR. Per-edge math
// bit-identical (absmax must stay 0.00390625). Cost: W-fragment LDS reads no longer
// amortized over 2 col-blocks -> LDS-pipe bound ~300-550us expected.

#define DEV __device__ __forceinline__

constexpr int NB = 8, NN = 50000, NE = 200000, DD = 16, HH = 128;
constexpr int TILE = 128;                  // edges per block-tile (8 waves x 16)
constexpr int BDIM = 512;
constexpr int GRID = 256;                  // persistent: 1 block per CU
constexpr int NTILE = NB * NE / TILE;      // 12500 exactly
constexpr float LNEPS = 1e-5f;

typedef __attribute__((ext_vector_type(8))) short short8v;  // 8 bf16 MFMA operand
typedef __attribute__((ext_vector_type(4))) float f32x4;    // MFMA accumulator

constexpr int W1_HALF = 128 * 32;
constexpr int W2_HALF = 128 * 128;
constexpr size_t SMEM_BYTES = (size_t)(2 * W1_HALF + 4 * W2_HALF) * sizeof(short)
                            + (size_t)(10 * HH + 1) * sizeof(float);

DEV void bsplit(float v, short& h, short& l) {
    unsigned u  = __builtin_bit_cast(unsigned, v);
    unsigned hb = (u + 0x8000u) & 0xFFFF0000u;      // bf16 RTN (half-up)
    float hf    = __builtin_bit_cast(float, hb);
    h = (short)(hb >> 16);
    float lf    = v - hf;                            // exact residual
    unsigned ul = __builtin_bit_cast(unsigned, lf);
    l = (short)((ul + 0x8000u) >> 16);
}

DEV f32x4 mf(short8v a, short8v b, f32x4 c) {
    return __builtin_amdgcn_mfma_f32_16x16x32_bf16(a, b, c, 0, 0, 0);
}

DEV float tanh_fast(float x) { return 1.0f - 2.0f / (1.0f + __expf(2.0f * x)); }

#define ZERO4 ((f32x4){0.f, 0.f, 0.f, 0.f})

// ---- straight-line generators; ALL state individually named ----

#define GATHER { \
    const int e = ebase + m; \
    const int2 nv = *(const int2*)(edges + 2 * (size_t)e); \
    const int b = e / NE; \
    const int n0 = min(max(nv.x, 0), NN - 1); \
    const int n1 = min(max(nv.y, 0), NN - 1); \
    const f32x4 f0 = *(const f32x4*)(nodes + (size_t)(b * NN + n0) * DD + 4 * g); \
    const f32x4 f1 = *(const f32x4*)(nodes + (size_t)(b * NN + n1) * DD + 4 * g); \
    short h, l; short8v vh, vl; \
    bsplit(f0[0], h, l); vh[0] = h; vl[0] = l; \
    bsplit(f0[1], h, l); vh[1] = h; vl[1] = l; \
    bsplit(f0[2], h, l); vh[2] = h; vl[2] = l; \
    bsplit(f0[3], h, l); vh[3] = h; vl[3] = l; \
    bsplit(f1[0], h, l); vh[4] = h; vl[4] = l; \
    bsplit(f1[1], h, l); vh[5] = h; vl[5] = l; \
    bsplit(f1[2], h, l); vh[6] = h; vl[6] = l; \
    bsplit(f1[3], h, l); vh[7] = h; vl[7] = l; \
    XH = vh; XL = vl; }

#define L1JT(jt) { \
    const int jr = 16 * jt + m; \
    const short8v wh = *(const short8v*)&W1h[jr * 32 + 8 * g]; \
    const short8v wl = *(const short8v*)&W1l[jr * 32 + 8 * g]; \
    f32x4 a = ZERO4; a = mf(wl, XH, a); a = mf(wh, XL, a); a = mf(wh, XH, a); AC##jt = a; }

#define EPI_ADDSUM(X, jt) { \
    const f32x4 bj = *(const f32x4*)&PB[16 * jt + 4 * g]; \
    X[0] += bj[0]; X[1] += bj[1]; X[2] += bj[2]; X[3] += bj[3]; \
    s += X[0] + X[1] + X[2] + X[3]; \
    s2 = fmaf(X[0], X[0], s2); s2 = fmaf(X[1], X[1], s2); \
    s2 = fmaf(X[2], X[2], s2); s2 = fmaf(X[3], X[3], s2); }

#define EPI_NORM(X, jt) { \
    const f32x4 gj = *(const f32x4*)&PB[HH + 16 * jt + 4 * g]; \
    const f32x4 bb = *(const f32x4*)&PB[2 * HH + 16 * jt + 4 * g]; \
    X[0] = tanh_fast((X[0] - mu) * rin * gj[0] + bb[0]); \
    X[1] = tanh_fast((X[1] - mu) * rin * gj[1] + bb[1]); \
    X[2] = tanh_fast((X[2] - mu) * rin * gj[2] + bb[2]); \
    X[3] = tanh_fast((X[3] - mu) * rin * gj[3] + bb[3]); }

#define EPI { \
    float s = 0.f, s2 = 0.f; \
    EPI_ADDSUM(AC0, 0) EPI_ADDSUM(AC1, 1) EPI_ADDSUM(AC2, 2) EPI_ADDSUM(AC3, 3) \
    EPI_ADDSUM(AC4, 4) EPI_ADDSUM(AC5, 5) EPI_ADDSUM(AC6, 6) EPI_ADDSUM(AC7, 7) \
    s += __shfl_xor(s, 16); s2 += __shfl_xor(s2, 16); \
    s += __shfl_xor(s, 32); s2 += __shfl_xor(s2, 32); \
    const float mu  = s * (1.f / HH); \
    const float var = fmaf(-mu, mu, s2 * (1.f / HH)); \
    const float rin = rsqrtf(var + LNEPS); \
    EPI_NORM(AC0, 0) EPI_NORM(AC1, 1) EPI_NORM(AC2, 2) EPI_NORM(AC3, 3) \
    EPI_NORM(AC4, 4) EPI_NORM(AC5, 5) EPI_NORM(AC6, 6) EPI_NORM(AC7, 7) }

// next-layer B-frag: slot i=4*h2+e <- AC[2c+h2][e]
#define TOF(c, SA, SB) { \
    short h, l; short8v vh, vl; \
    bsplit(SA[0], h, l); vh[0] = h; vl[0] = l; \
    bsplit(SA[1], h, l); vh[1] = h; vl[1] = l; \
    bsplit(SA[2], h, l); vh[2] = h; vl[2] = l; \
    bsplit(SA[3], h, l); vh[3] = h; vl[3] = l; \
    bsplit(SB[0], h, l); vh[4] = h; vl[4] = l; \
    bsplit(SB[1], h, l); vh[5] = h; vl[5] = l; \
    bsplit(SB[2], h, l); vh[6] = h; vl[6] = l; \
    bsplit(SB[3], h, l); vh[7] = h; vl[7] = l; \
    FH##c = vh; FL##c = vl; }

#define TOFRAGS_ALL \
    TOF(0, AC0, AC1) TOF(1, AC2, AC3) TOF(2, AC4, AC5) TOF(3, AC6, AC7)

#define ZACC \
    AC0 = ZERO4; AC1 = ZERO4; AC2 = ZERO4; AC3 = ZERO4; \
    AC4 = ZERO4; AC5 = ZERO4; AC6 = ZERO4; AC7 = ZERO4;

#define GSTEP(c, jt) { \
    const int jr = 16 * jt + m; \
    const unsigned off = (unsigned)(jr * 256 + (32 * c + 8 * g) * 2) \
                       ^ ((unsigned)(jr & 7) << 4); \
    const short8v wh = *(const short8v*)((const char*)Wh + off); \
    const short8v wl = *(const short8v*)((const char*)Wl + off); \
    AC##jt = mf(wl, FH##c, AC##jt); \
    AC##jt = mf(wh, FL##c, AC##jt); \
    AC##jt = mf(wh, FH##c, AC##jt); }

#define GLAYER \
    ZACC \
    GSTEP(0, 0) GSTEP(0, 1) GSTEP(0, 2) GSTEP(0, 3) \
    GSTEP(0, 4) GSTEP(0, 5) GSTEP(0, 6) GSTEP(0, 7) \
    GSTEP(1, 0) GSTEP(1, 1) GSTEP(1, 2) GSTEP(1, 3) \
    GSTEP(1, 4) GSTEP(1, 5) GSTEP(1, 6) GSTEP(1, 7) \
    GSTEP(2, 0) GSTEP(2, 1) GSTEP(2, 2) GSTEP(2, 3) \
    GSTEP(2, 4) GSTEP(2, 5) GSTEP(2, 6) GSTEP(2, 7) \
    GSTEP(3, 0) GSTEP(3, 1) GSTEP(3, 2) GSTEP(3, 3) \
    GSTEP(3, 4) GSTEP(3, 5) GSTEP(3, 6) GSTEP(3, 7)

#define L4JT(jt) { \
    const f32x4 w4v = *(const f32x4*)&P[9 * HH + 16 * jt + 4 * g]; \
    s = fmaf(AC##jt[0], w4v[0], s); s = fmaf(AC##jt[1], w4v[1], s); \
    s = fmaf(AC##jt[2], w4v[2], s); s = fmaf(AC##jt[3], w4v[3], s); }

#define L4DOT { \
    float s = 0.f; \
    L4JT(0) L4JT(1) L4JT(2) L4JT(3) L4JT(4) L4JT(5) L4JT(6) L4JT(7) \
    s += __shfl_xor(s, 16); \
    s += __shfl_xor(s, 32); \
    if (g == 0) out[ebase + m] = 1.f / (1.f + __expf(-(s + bb4))); }

extern "C" __global__ __launch_bounds__(BDIM)
__attribute__((amdgpu_waves_per_eu(2, 2)))
void edge_mlp(
    const float* __restrict__ nodes, const int* __restrict__ edges,
    const float* __restrict__ W1, const float* __restrict__ b1,
    const float* __restrict__ g1, const float* __restrict__ be1,
    const float* __restrict__ W2, const float* __restrict__ b2,
    const float* __restrict__ g2, const float* __restrict__ be2,
    const float* __restrict__ W3, const float* __restrict__ b3,
    const float* __restrict__ g3, const float* __restrict__ be3,
    const float* __restrict__ W4, const float* __restrict__ b4,
    float* __restrict__ out) {

    extern __shared__ char smem[];
    short* W1h = (short*)smem;
    short* W1l = W1h + W1_HALF;
    short* W2h = W1l + W1_HALF;
    short* W2l = W2h + W2_HALF;
    short* W3h = W2l + W2_HALF;
    short* W3l = W3h + W2_HALF;
    float* P   = (float*)(W3l + W2_HALF);   // [0..2]=L1 b,g,be  [3..5]=L2  [6..8]=L3  [9]=W4  [10*128]=b4

    const int tid = threadIdx.x;

    // ---- one-time weight staging: k = 32c+16h2+4g+e -> kk = 32c+8g+4h2+e ----
    for (int i = tid; i < 32 * 128; i += BDIM) {
        int k = i >> 7, j = i & 127;
        short h, l; bsplit(W1[i], h, l);
        int kk = 8 * ((k >> 2) & 3) + 4 * (k >> 4) + (k & 3);
        W1h[j * 32 + kk] = h;
        W1l[j * 32 + kk] = l;
    }
    for (int i = tid; i < 128 * 128; i += BDIM) {
        int k = i >> 7, j = i & 127;
        int kk = 32 * (k >> 5) + 8 * ((k >> 2) & 3) + 4 * ((k >> 4) & 1) + (k & 3);
        unsigned off = (unsigned)(j * 256 + kk * 2) ^ ((unsigned)(j & 7) << 4);
        short h, l;
        bsplit(W2[i], h, l);
        *(short*)((char*)W2h + off) = h;  *(short*)((char*)W2l + off) = l;
        bsplit(W3[i], h, l);
        *(short*)((char*)W3h + off) = h;  *(short*)((char*)W3l + off) = l;
    }
    if (tid < HH) {
        P[0*HH+tid] = b1[tid]; P[1*HH+tid] = g1[tid]; P[2*HH+tid] = be1[tid];
        P[3*HH+tid] = b2[tid]; P[4*HH+tid] = g2[tid]; P[5*HH+tid] = be2[tid];
        P[6*HH+tid] = b3[tid]; P[7*HH+tid] = g3[tid]; P[8*HH+tid] = be3[tid];
        P[9*HH+tid] = W4[tid];
        if (tid == 0) P[10*HH] = b4[0];
    }
    __syncthreads();

    const int lane = tid & 63;
    const int wv   = tid >> 6;
    const int m    = lane & 15;     // A-role: feature row in 16-tile; B-role: edge col
    const int g    = lane >> 4;     // k-slot group

    for (int t = blockIdx.x; t < NTILE; t += GRID) {
        const int ebase = t * TILE + wv * 16;

        // ~100 VGPRs of named state: fits under the observed 128 ceiling
        f32x4 AC0, AC1, AC2, AC3, AC4, AC5, AC6, AC7;
        short8v FH0, FH1, FH2, FH3;
        short8v FL0, FL1, FL2, FL3;
        short8v XH, XL;

        GATHER

        // layer 1 (K=32)
        L1JT(0) L1JT(1) L1JT(2) L1JT(3) L1JT(4) L1JT(5) L1JT(6) L1JT(7)
        { const float* PB = P;          EPI }
        TOFRAGS_ALL

        // layer 2 (K=128)
        { const short* Wh = W2h; const short* Wl = W2l; GLAYER }
        { const float* PB = P + 3 * HH; EPI }
        TOFRAGS_ALL

        // layer 3 (K=128)
        { const short* Wh = W3h; const short* Wl = W3l; GLAYER }
        { const float* PB = P + 6 * HH; EPI }

        // layer 4 + sigmoid
        const float bb4 = P[10 * HH];
        L4DOT
    }
}

extern "C" void kernel_launch(void* const* d_in, const int* in_sizes, int n_in,
                              void* d_out, int out_size, void* d_ws, size_t ws_size,
                              hipStream_t stream) {
    (void)in_sizes; (void)n_in; (void)d_ws; (void)ws_size; (void)out_size;
    const float* nodes = (const float*)d_in[0];
    const int*   edges = (const int*)d_in[1];     // harness: integer inputs arrive as int32
    const float *W1 = (const float*)d_in[2],  *b1  = (const float*)d_in[3];
    const float *g1 = (const float*)d_in[4],  *be1 = (const float*)d_in[5];
    const float *W2 = (const float*)d_in[6],  *b2  = (const float*)d_in[7];
    const float *g2 = (const float*)d_in[8],  *be2 = (const float*)d_in[9];
    const float *W3 = (const float*)d_in[10], *b3  = (const float*)d_in[11];
    const float *g3 = (const float*)d_in[12], *be3 = (const float*)d_in[13];
    const float *W4 = (const float*)d_in[14], *b4  = (const float*)d_in[15];
    float* out = (float*)d_out;

    hipFuncSetAttribute(reinterpret_cast<const void*>(&edge_mlp),
                        hipFuncAttributeMaxDynamicSharedMemorySize, (int)SMEM_BYTES);

    edge_mlp<<<GRID, BDIM, SMEM_BYTES, stream>>>(nodes, edges,
                                                 W1, b1, g1, be1,
                                                 W2, b2, g2, be2,
                                                 W3, b3, g3, be3,
                                                 W4, b4, out);
}